// Round 2
// baseline (506.952 us; speedup 1.0000x reference)
//
#include <hip/hip_runtime.h>

// 1-NN (squared-L2 argmin over 500000x256 f32 keys) + dot(values[idx], query).
// Memory-bound: 512 MB of keys stream once -> ~81 us floor at 6.3 TB/s.
// Single fused kernel: per-block atomicMax on packed key, last-block-done
// pattern does the final values[idx]@query dot (saves a dispatch + tail).

#define D 256
#define D4 (D / 4)            // 64 float4 per row == one wave-wide 1 KB load
#define BLOCK 256
#define GRID 2048             // 8 blocks/CU, 8192 waves, ~62 rows per wave

typedef float f32x4 __attribute__((ext_vector_type(4)));

// Monotonic float->uint map (inputs are finite gaussians, no NaN).
__device__ __forceinline__ unsigned int fkey(float f) {
    unsigned int u = __float_as_uint(f);
    return (u & 0x80000000u) ? ~u : (u | 0x80000000u);
}
// Packed so that LARGER u64 == (smaller dist, then lower row).
// ~fkey >= 0x00800000 for any finite float -> packed > 0 always, so 0 is a
// safe identity for atomicMax (lets one memset(0) init both best and counter).
__device__ __forceinline__ unsigned long long packbest(float d, int row) {
    return ((unsigned long long)(~fkey(d)) << 32) | (unsigned int)~(unsigned int)row;
}

__device__ __forceinline__ float rowpart(f32x4 a, f32x4 qm2) {
    return a.x * (a.x + qm2.x) + a.y * (a.y + qm2.y)
         + a.z * (a.z + qm2.z) + a.w * (a.w + qm2.w);
}

__global__ __launch_bounds__(BLOCK) void nn_fused_kernel(
    const float* __restrict__ query,
    const float* __restrict__ keys,
    const float* __restrict__ values,
    unsigned long long* __restrict__ best,    // d_ws[0], init 0
    unsigned int* __restrict__ counter,       // d_ws[8..], init 0
    float* __restrict__ out,
    int N)
{
    const int lane  = threadIdx.x & 63;
    const int wib   = threadIdx.x >> 6;
    const int wpb   = BLOCK >> 6;
    const int gwave = blockIdx.x * wpb + wib;
    const int nwav  = GRID * wpb;

    const f32x4 q   = reinterpret_cast<const f32x4*>(query)[lane];
    const f32x4 qm2 = -2.f * q;

    const int chunk = (N + nwav - 1) / nwav;
    const int r0 = gwave * chunk;
    const int r1 = min(N, r0 + chunk);

    unsigned long long myBest = 0ull;
    const f32x4* __restrict__ k4 = reinterpret_cast<const f32x4*>(keys);

    int r = r0;
    // 4 rows per iteration: 4 KB contiguous loads in flight, 4 independent
    // shuffle-reduce chains interleave to hide ds_bpermute latency.
    for (; r + 3 < r1; r += 4) {
        f32x4 a0 = __builtin_nontemporal_load(&k4[(size_t)(r + 0) * D4 + lane]);
        f32x4 a1 = __builtin_nontemporal_load(&k4[(size_t)(r + 1) * D4 + lane]);
        f32x4 a2 = __builtin_nontemporal_load(&k4[(size_t)(r + 2) * D4 + lane]);
        f32x4 a3 = __builtin_nontemporal_load(&k4[(size_t)(r + 3) * D4 + lane]);
        float p0 = rowpart(a0, qm2);
        float p1 = rowpart(a1, qm2);
        float p2 = rowpart(a2, qm2);
        float p3 = rowpart(a3, qm2);
        #pragma unroll
        for (int off = 32; off; off >>= 1) {
            p0 += __shfl_down(p0, off, 64);
            p1 += __shfl_down(p1, off, 64);
            p2 += __shfl_down(p2, off, 64);
            p3 += __shfl_down(p3, off, 64);
        }
        if (lane == 0) {
            unsigned long long b0 = packbest(p0, r + 0);
            unsigned long long b1 = packbest(p1, r + 1);
            unsigned long long b2 = packbest(p2, r + 2);
            unsigned long long b3 = packbest(p3, r + 3);
            b0 = max(b0, b1); b2 = max(b2, b3);
            b0 = max(b0, b2);
            if (b0 > myBest) myBest = b0;
        }
    }
    for (; r < r1; ++r) {
        f32x4 a0 = __builtin_nontemporal_load(&k4[(size_t)r * D4 + lane]);
        float p0 = rowpart(a0, qm2);
        #pragma unroll
        for (int off = 32; off; off >>= 1) p0 += __shfl_down(p0, off, 64);
        if (lane == 0) {
            unsigned long long b0 = packbest(p0, r);
            if (b0 > myBest) myBest = b0;
        }
    }

    // Block reduction -> one device-scope atomic per block.
    __shared__ unsigned long long s_best[wpb];
    if (lane == 0) s_best[wib] = myBest;
    __syncthreads();
    if (threadIdx.x == 0) {
        unsigned long long m = s_best[0];
        #pragma unroll
        for (int i = 1; i < wpb; ++i) m = max(m, s_best[i]);
        if (m) atomicMax(best, m);
    }

    // Last-block-done: order best-atomic before counter-atomic, then the
    // final arriving block reads the global best and does the 256-dim dot.
    __threadfence();
    __shared__ bool amLast;
    if (threadIdx.x == 0)
        amLast = (atomicAdd(counter, 1u) == GRID - 1);
    __syncthreads();
    if (amLast) {
        __shared__ int s_idx;
        if (threadIdx.x == 0) {
            unsigned long long b = atomicMax(best, 0ull);  // coherent read
            s_idx = (int)~(unsigned int)(b & 0xFFFFFFFFull);
        }
        __syncthreads();
        if (threadIdx.x < 64) {
            const f32x4 v = reinterpret_cast<const f32x4*>(values)[(size_t)s_idx * D4 + lane];
            float dsum = v.x * q.x + v.y * q.y + v.z * q.z + v.w * q.w;
            #pragma unroll
            for (int off = 32; off; off >>= 1) dsum += __shfl_down(dsum, off, 64);
            if (lane == 0) out[0] = dsum;
        }
    }
}

extern "C" void kernel_launch(void* const* d_in, const int* in_sizes, int n_in,
                              void* d_out, int out_size, void* d_ws, size_t ws_size,
                              hipStream_t stream) {
    const float* query  = (const float*)d_in[0];
    const float* keys   = (const float*)d_in[1];
    const float* values = (const float*)d_in[2];
    const int N = in_sizes[1] / D;

    unsigned long long* best = (unsigned long long*)d_ws;
    unsigned int* counter = (unsigned int*)((char*)d_ws + 8);
    // ws is NOT re-poisoned between replays -> init every call (capture-safe).
    hipMemsetAsync(d_ws, 0, 16, stream);

    nn_fused_kernel<<<GRID, BLOCK, 0, stream>>>(query, keys, values, best,
                                                counter, (float*)d_out, N);
}

// Round 3
// 96.761 us; speedup vs baseline: 5.2392x; 5.2392x over previous
//
#include <hip/hip_runtime.h>

// 1-NN (squared-L2 argmin over 500000x256 f32 keys) + dot(values[idx], query).
// Memory-bound: 512 MB of keys stream once -> ~81 us floor at 6.3 TB/s.
// R3: revert R2's regressions (nontemporal loads, __threadfence fusion).
// Structure = R1 (plain loads, 2 rows/iter, wave-per-row) but block results
// go to d_ws[blockIdx] via plain stores (no memset dispatch, no atomics);
// kernel 2 reduces the 2048 entries and does the final dot.

#define D 256
#define D4 (D / 4)            // 64 float4 per row == one wave-wide 1 KB load
#define BLOCK 256
#define GRID 2048             // 8 blocks/CU, 8192 waves, ~62 rows per wave

// Monotonic float->uint map (inputs are finite gaussians, no NaN).
__device__ __forceinline__ unsigned int fkey(float f) {
    unsigned int u = __float_as_uint(f);
    return (u & 0x80000000u) ? ~u : (u | 0x80000000u);
}

__global__ __launch_bounds__(BLOCK) void nn_argmin_kernel(
    const float* __restrict__ query,
    const float* __restrict__ keys,
    unsigned long long* __restrict__ blockBest,  // d_ws, GRID entries
    int N)
{
    const int lane  = threadIdx.x & 63;
    const int wib   = threadIdx.x >> 6;               // wave in block
    const int wpb   = BLOCK >> 6;                     // waves per block
    const int gwave = blockIdx.x * wpb + wib;
    const int nwav  = GRID * wpb;

    // Per-lane query fragment (constant across rows).
    const float4 q = reinterpret_cast<const float4*>(query)[lane];
    const float4 qm2 = make_float4(-2.f * q.x, -2.f * q.y, -2.f * q.z, -2.f * q.w);

    // Contiguous chunk of rows per wave (streams ~62 KB contiguously).
    const int chunk = (N + nwav - 1) / nwav;
    const int r0 = gwave * chunk;
    const int r1 = min(N, r0 + chunk);

    unsigned long long myBest = 0xFFFFFFFFFFFFFFFFull;  // smaller == better

    const float4* __restrict__ k4 = reinterpret_cast<const float4*>(keys);

    int r = r0;
    // 2 rows per iteration: two independent 1 KB loads in flight per wave,
    // two shuffle-reduce chains interleaved.
    for (; r + 1 < r1; r += 2) {
        float4 a = k4[(size_t)r       * D4 + lane];
        float4 b = k4[(size_t)(r + 1) * D4 + lane];
        float pa = a.x * (a.x + qm2.x) + a.y * (a.y + qm2.y)
                 + a.z * (a.z + qm2.z) + a.w * (a.w + qm2.w);
        float pb = b.x * (b.x + qm2.x) + b.y * (b.y + qm2.y)
                 + b.z * (b.z + qm2.z) + b.w * (b.w + qm2.w);
        #pragma unroll
        for (int off = 32; off; off >>= 1) {
            pa += __shfl_down(pa, off, 64);
            pb += __shfl_down(pb, off, 64);
        }
        if (lane == 0) {
            unsigned long long ka = ((unsigned long long)fkey(pa) << 32) | (unsigned int)r;
            unsigned long long kb = ((unsigned long long)fkey(pb) << 32) | (unsigned int)(r + 1);
            if (ka < myBest) myBest = ka;
            if (kb < myBest) myBest = kb;
        }
    }
    if (r < r1) {
        float4 a = k4[(size_t)r * D4 + lane];
        float pa = a.x * (a.x + qm2.x) + a.y * (a.y + qm2.y)
                 + a.z * (a.z + qm2.z) + a.w * (a.w + qm2.w);
        #pragma unroll
        for (int off = 32; off; off >>= 1) pa += __shfl_down(pa, off, 64);
        if (lane == 0) {
            unsigned long long ka = ((unsigned long long)fkey(pa) << 32) | (unsigned int)r;
            if (ka < myBest) myBest = ka;
        }
    }

    // Block reduction in LDS, then ONE plain store per block (no atomics,
    // every slot overwritten every call -> no init dispatch needed).
    __shared__ unsigned long long s_best[wpb];
    if (lane == 0) s_best[wib] = myBest;
    __syncthreads();
    if (threadIdx.x == 0) {
        unsigned long long m = s_best[0];
        #pragma unroll
        for (int i = 1; i < wpb; ++i) m = min(m, s_best[i]);
        blockBest[blockIdx.x] = m;
    }
}

__global__ __launch_bounds__(BLOCK) void nn_finish_kernel(
    const float* __restrict__ query,
    const float* __restrict__ values,
    const unsigned long long* __restrict__ blockBest,
    float* __restrict__ out)
{
    const int tid  = threadIdx.x;
    const int lane = tid & 63;
    const int wib  = tid >> 6;

    // Min-reduce GRID packed entries (16 KB), coalesced.
    unsigned long long m = 0xFFFFFFFFFFFFFFFFull;
    #pragma unroll
    for (int i = 0; i < GRID / BLOCK; ++i)
        m = min(m, blockBest[i * BLOCK + tid]);
    #pragma unroll
    for (int off = 32; off; off >>= 1)
        m = min(m, __shfl_down(m, off, 64));

    __shared__ unsigned long long s_best[BLOCK / 64];
    __shared__ int s_idx;
    if (lane == 0) s_best[wib] = m;
    __syncthreads();
    if (tid == 0) {
        unsigned long long mm = s_best[0];
        #pragma unroll
        for (int i = 1; i < BLOCK / 64; ++i) mm = min(mm, s_best[i]);
        s_idx = (int)(mm & 0xFFFFFFFFull);
    }
    __syncthreads();

    if (tid < 64) {
        const float4 v = reinterpret_cast<const float4*>(values)[(size_t)s_idx * D4 + lane];
        const float4 q = reinterpret_cast<const float4*>(query)[lane];
        float d = v.x * q.x + v.y * q.y + v.z * q.z + v.w * q.w;
        #pragma unroll
        for (int off = 32; off; off >>= 1) d += __shfl_down(d, off, 64);
        if (lane == 0) out[0] = d;
    }
}

extern "C" void kernel_launch(void* const* d_in, const int* in_sizes, int n_in,
                              void* d_out, int out_size, void* d_ws, size_t ws_size,
                              hipStream_t stream) {
    const float* query  = (const float*)d_in[0];
    const float* keys   = (const float*)d_in[1];
    const float* values = (const float*)d_in[2];
    const int N = in_sizes[1] / D;

    unsigned long long* blockBest = (unsigned long long*)d_ws;  // 16 KB used

    nn_argmin_kernel<<<GRID, BLOCK, 0, stream>>>(query, keys, blockBest, N);
    nn_finish_kernel<<<1, BLOCK, 0, stream>>>(query, values, blockBest,
                                              (float*)d_out);
}